// Round 2
// baseline (767.204 us; speedup 1.0000x reference)
//
#include <hip/hip_runtime.h>
#include <cstdint>

// MemNet, fully fused (plain launch + hand-rolled grid barrier):
// all hops reduced to scalar recursions over
// Q[b,l,j] = v_loc[b,l] * (mem[b,l] . M_j),  25 projection columns:
//   col 0        : w0 = w_attn[0:D]          (scores)
//   col 1+k      : U_k = W_lin^k u, k=0..5   (u = w_attn[D:2D])
//   col 7+6c+k   : Y_{k,c} = W_lin^k W_out[:,c], k=0..5
//   col 25+c     : Y_{6,c}  (only dotted with v_aspect)
// One kernel: init -> 6 chain steps (emb prefetch into L3 overlapped)
// -> Q gemm -> per-batch hop recursion. 512 blocks x 256 threads,
// exactly 2 blocks/CU co-resident (LDS 59392 B, launch_bounds(256,2)),
// so a counter-based grid barrier is safe without cooperative launch.
// Cross-XCD coherence: __threadfence() (buffer_wbl2/buffer_inv sc1)
// around each barrier publishes Mt/Mc/Q across per-XCD L2s.

#define DD 1024
#define LL 512
#define MTS 32
#define NBLK 512u

__device__ unsigned g_cnt[8];   // static device mem: zeroed at load, NOT ws-poisoned

__device__ __forceinline__ void gbar(int k)
{
  __syncthreads();
  if (threadIdx.x == 0) {
    __threadfence();  // agent release: write back this XCD's L2
    unsigned t = __hip_atomic_fetch_add(&g_cnt[k], 1u, __ATOMIC_RELAXED,
                                        __HIP_MEMORY_SCOPE_AGENT);
    unsigned tgt = (t / NBLK + 1u) * NBLK;  // monotonic: survives graph replays
    int guard = 0;
    while (__hip_atomic_load(&g_cnt[k], __ATOMIC_RELAXED,
                             __HIP_MEMORY_SCOPE_AGENT) < tgt) {
      __builtin_amdgcn_s_sleep(2);
      if (++guard > (1 << 22)) break;  // fail loud, never hang
    }
    __threadfence();  // agent acquire: invalidate L1/L2 so reads are fresh
  }
  __syncthreads();
}

union SMem {
  struct { float stag[4][64 * 33]; float qp[4][64][25]; } g;        // 59392 B
  struct { float Qs[25 * LL]; float va[DD]; float red[36 * 4]; } h; // 55872 B
};

__device__ __forceinline__ void keep4(float4 v) {
  asm volatile("" :: "v"(v.x), "v"(v.y), "v"(v.z), "v"(v.w));
}

// prefetch 10 context-embedding rows (4 KB each) of this block's tile into L3
__device__ __forceinline__ void prefetch10(const int* __restrict__ ctx_ids,
                                           const float* __restrict__ emb,
                                           int rowbase, int tid, int ph)
{
  float4 v[10];
  int r0 = ph * 10;
#pragma unroll
  for (int rr = 0; rr < 10; ++rr) {
    int r = r0 + rr; if (r > 63) r = 63;   // tail dupes are cache-hits
    int rid = ctx_ids[rowbase + r];
    v[rr] = ((const float4*)(emb + (size_t)rid * DD))[tid];
  }
#pragma unroll
  for (int rr = 0; rr < 10; ++rr) keep4(v[rr]);
}

template <bool ISMAX>
__device__ __forceinline__ void breduce(float* v, int n, float* lds, int tid)
{
  int wv = __builtin_amdgcn_readfirstlane(tid >> 6);
  int ln = tid & 63;
  for (int q = 0; q < n; ++q) {
    float x = v[q];
#pragma unroll
    for (int m = 1; m < 64; m <<= 1) {
      float o = __shfl_xor(x, m, 64);
      x = ISMAX ? fmaxf(x, o) : x + o;
    }
    if (ln == 0) lds[q * 4 + wv] = x;
  }
  __syncthreads();
  for (int q = 0; q < n; ++q) {
    float a = lds[q * 4 + 0], b = lds[q * 4 + 1];
    float c = lds[q * 4 + 2], d = lds[q * 4 + 3];
    v[q] = ISMAX ? fmaxf(fmaxf(a, b), fmaxf(c, d)) : ((a + b) + (c + d));
  }
  __syncthreads();
}

__global__ __launch_bounds__(256, 2) void k_all(
    const int* __restrict__ ctx_ids, const int* __restrict__ tgt_ids,
    const int* __restrict__ ctx_len, const int* __restrict__ tgt_len,
    const int* __restrict__ toff,    const float* __restrict__ emb,
    const float* __restrict__ Wl,    const float* __restrict__ bl,
    const float* __restrict__ wat,   const float* __restrict__ bat,
    const float* __restrict__ bo,    const float* __restrict__ Wo,
    float* __restrict__ Mt, float* __restrict__ Mc,
    float* __restrict__ Q,  float* __restrict__ out)
{
  __shared__ SMem sm;
  const int tid = threadIdx.x;
  const int bid = blockIdx.x;
  const int wv  = __builtin_amdgcn_readfirstlane(tid >> 6);
  const int ln  = tid & 63;
  const int rowbase = bid * 64;

  // ---------------- phase 0: init base projection columns + prefetch ----
  if (bid < 4) {
    int d = bid * 256 + tid;
    float w0 = wat[d], u0 = wat[DD + d];
    Mt[d * MTS + 0] = w0; Mc[0 * DD + d] = w0;
    Mt[d * MTS + 1] = u0; Mc[1 * DD + d] = u0;
#pragma unroll
    for (int c = 0; c < 3; ++c) {
      float y = Wo[d * 3 + c];
      int col = 7 + 6 * c;
      Mt[d * MTS + col] = y; Mc[col * DD + d] = y;
    }
  }
  prefetch10(ctx_ids, emb, rowbase, tid, 0);
  gbar(0);

  // ---------------- phases 1..6: chain steps (Mc col math) + prefetch ---
  for (int s = 1; s <= 6; ++s) {
    if (wv < 2) {
      int i = bid * 2 + wv;                   // 1024 rows over 512 blocks
      const float* wrow = Wl + (size_t)i * DD;
      int c0 = (s <= 5) ? s : 0;              // s=6 has no U-chain input
      int c1 = 6 + s, c2 = 12 + s, c3 = 18 + s;
      float s0 = 0.f, s1 = 0.f, s2 = 0.f, s3 = 0.f;
      for (int m = 0; m < 16; ++m) {
        int j = ln + m * 64;
        float w = wrow[j];
        s0 += w * Mc[c0 * DD + j];
        s1 += w * Mc[c1 * DD + j];
        s2 += w * Mc[c2 * DD + j];
        s3 += w * Mc[c3 * DD + j];
      }
#pragma unroll
      for (int m = 1; m < 64; m <<= 1) {
        s0 += __shfl_xor(s0, m, 64); s1 += __shfl_xor(s1, m, 64);
        s2 += __shfl_xor(s2, m, 64); s3 += __shfl_xor(s3, m, 64);
      }
      if (ln == 0) {
        if (s <= 5) { Mt[i * MTS + 1 + s] = s0; Mc[(1 + s) * DD + i] = s0; }
        int o1 = (s <= 5) ? 7 + s  : 25;
        int o2 = (s <= 5) ? 13 + s : 26;
        int o3 = (s <= 5) ? 19 + s : 27;
        Mt[i * MTS + o1] = s1; Mc[o1 * DD + i] = s1;
        Mt[i * MTS + o2] = s2; Mc[o2 * DD + i] = s2;
        Mt[i * MTS + o3] = s3; Mc[o3 * DD + i] = s3;
      }
    }
    prefetch10(ctx_ids, emb, rowbase, tid, s);
    gbar(s);
  }

  // ---------------- phase 7: Q gemm  (block = 64 ctx rows, wave = k-quarter)
  {
    float* sw = sm.g.stag[wv];
    int myid = ctx_ids[rowbase + ln];
    const float* base[8];
#pragma unroll
    for (int ii = 0; ii < 8; ++ii) {
      int rid = __shfl(myid, ii * 8 + (ln >> 3), 64);
      base[ii] = emb + (size_t)rid * DD;
    }
    int p4 = (ln & 7) * 4;
    int k0 = wv * 256;
    float acc[25];
#pragma unroll
    for (int j = 0; j < 25; ++j) acc[j] = 0.f;

    float4 buf[8];
#pragma unroll
    for (int ii = 0; ii < 8; ++ii)
      buf[ii] = *(const float4*)(base[ii] + k0 + p4);

    for (int ch = 0; ch < 8; ++ch) {
#pragma unroll
      for (int ii = 0; ii < 8; ++ii) {
        int r = ii * 8 + (ln >> 3);
        int a = r * 33 + p4;
        sw[a + 0] = buf[ii].x; sw[a + 1] = buf[ii].y;
        sw[a + 2] = buf[ii].z; sw[a + 3] = buf[ii].w;
      }
      if (ch < 7) {
        int kb = k0 + (ch + 1) * 32;
#pragma unroll
        for (int ii = 0; ii < 8; ++ii)
          buf[ii] = *(const float4*)(base[ii] + kb + p4);
      }
      __builtin_amdgcn_s_waitcnt(0xc07f);  // lgkmcnt(0): same-wave LDS visibility
      const float* mrow = Mt + (size_t)(k0 + ch * 32) * MTS;  // wave-uniform
#pragma unroll 4
      for (int kk = 0; kk < 32; ++kk) {
        float mv = sw[ln * 33 + kk];
#pragma unroll
        for (int j = 0; j < 25; ++j) acc[j] += mv * mrow[kk * MTS + j];
      }
    }
#pragma unroll
    for (int j = 0; j < 25; ++j) sm.g.qp[wv][ln][j] = acc[j];
    __syncthreads();

    int b = rowbase >> 9;
    int l0 = rowbase & 511;
    int clen = ctx_len[b];
    int off = toff[b];
    float fclen = (float)clen;
    for (int i = tid; i < 1600; i += 256) {
      int j = i >> 6, r = i & 63;
      float s = sm.g.qp[0][r][j] + sm.g.qp[1][r][j] +
                sm.g.qp[2][r][j] + sm.g.qp[3][r][j];
      int l = l0 + r;
      float vl = (l < clen) ? (1.f - fabsf((float)(l - off)) / fclen) : 0.f;
      Q[((size_t)b * 25 + j) * LL + l] = s * vl;
    }
  }
  gbar(7);

  // ---------------- phase 8: per-batch hop recursion (blocks 0..63) -----
  if (bid >= 64) return;
  {
    float* Qs = sm.h.Qs;
    float* va = sm.h.va;
    float* red = sm.h.red;
    int b = bid;

    for (int i = tid; i < 25 * LL; i += 256)
      Qs[i] = Q[(size_t)b * (25 * LL) + i];

    int tl = tgt_len[b];
    float inv_tl = 1.f / (float)tl;
    for (int d = tid; d < DD; d += 256) {
      float s = 0.f;
#pragma unroll
      for (int t = 0; t < 8; ++t)
        if (t < tl) s += emb[(size_t)tgt_ids[b * 8 + t] * DD + d];
      va[d] = s * inv_tl;
    }
    __syncthreads();

    // 32 dots: p[0..5]=va.U_k, p[6..8]=va.Y6c, p[9..13]=b.U_k(k<5), p[14+6c+k]=b.Y_{k,c}
    float p[32];
#pragma unroll
    for (int q = 0; q < 32; ++q) p[q] = 0.f;
    for (int d = tid; d < DD; d += 256) {
      float vad = va[d], bd = bl[d];
#pragma unroll
      for (int k = 0; k < 6; ++k) {
        float u = Mc[(1 + k) * DD + d];
        p[k] += vad * u;
        if (k < 5) p[9 + k] += bd * u;
      }
#pragma unroll
      for (int c = 0; c < 3; ++c) {
        p[6 + c] += vad * Mc[(25 + c) * DD + d];
#pragma unroll
        for (int k = 0; k < 6; ++k)
          p[14 + c * 6 + k] += bd * Mc[(7 + 6 * c + k) * DD + d];
      }
    }
    breduce<false>(p, 32, red, tid);

    float tcur[6], rc[3], beta[5], gam[18];
#pragma unroll
    for (int k = 0; k < 6; ++k) tcur[k] = p[k];
#pragma unroll
    for (int c = 0; c < 3; ++c) rc[c] = p[6 + c];
#pragma unroll
    for (int k = 0; k < 5; ++k) beta[k] = p[9 + k];
#pragma unroll
    for (int q = 0; q < 18; ++q) gam[q] = p[14 + q];

    int clen = ctx_len[b];
    float batt = bat[0];
    int l1 = tid, l2 = tid + 256;

    for (int h = 0; h < 6; ++h) {
      float s_h = tcur[0];
      float sc1 = -1e30f, sc2 = -1e30f;
      if (l1 < clen) sc1 = tanhf(Qs[l1] + s_h + batt);
      if (l2 < clen) sc2 = tanhf(Qs[l2] + s_h + batt);
      float mx = fmaxf(sc1, sc2);
      breduce<true>(&mx, 1, red, tid);

      float pe[9];
#pragma unroll
      for (int q = 0; q < 9; ++q) pe[q] = 0.f;
      int kd = 5 - h;
      if (l1 < clen) {
        float e = expf(sc1 - mx);
        pe[0] += e;
        for (int k = 0; k <= 4 - h; ++k) pe[1 + k] += e * Qs[(1 + k) * LL + l1];
#pragma unroll
        for (int c = 0; c < 3; ++c) pe[6 + c] += e * Qs[(7 + 6 * c + kd) * LL + l1];
      }
      if (l2 < clen) {
        float e = expf(sc2 - mx);
        pe[0] += e;
        for (int k = 0; k <= 4 - h; ++k) pe[1 + k] += e * Qs[(1 + k) * LL + l2];
#pragma unroll
        for (int c = 0; c < 3; ++c) pe[6 + c] += e * Qs[(7 + 6 * c + kd) * LL + l2];
      }
      breduce<false>(pe, 9, red, tid);

      float invS = 1.f / pe[0];
      for (int k = 0; k <= 4 - h; ++k)
        tcur[k] = pe[1 + k] * invS + tcur[k + 1] + beta[k];
#pragma unroll
      for (int c = 0; c < 3; ++c)
        rc[c] = pe[6 + c] * invS + rc[c] + gam[c * 6 + kd];
    }
    if (tid < 3) out[b * 3 + tid] = rc[tid] + bo[tid];
  }
}

extern "C" void kernel_launch(void* const* d_in, const int* in_sizes, int n_in,
                              void* d_out, int out_size, void* d_ws, size_t ws_size,
                              hipStream_t stream)
{
  const int*   ctx_ids = (const int*)d_in[0];
  const int*   tgt_ids = (const int*)d_in[1];
  const int*   ctx_len = (const int*)d_in[2];
  const int*   tgt_len = (const int*)d_in[3];
  const int*   toff    = (const int*)d_in[4];
  const float* emb     = (const float*)d_in[5];
  const float* Wl      = (const float*)d_in[6];
  const float* bl      = (const float*)d_in[7];
  const float* wat     = (const float*)d_in[8];
  const float* bat     = (const float*)d_in[9];
  const float* Wo      = (const float*)d_in[10];
  const float* bo      = (const float*)d_in[11];
  float* ws = (float*)d_ws;
  float* Mt = ws;                 // 1024*32
  float* Mc = ws + 32768;         // 32*1024
  float* Q  = ws + 65536;         // 64*25*512
  float* outp = (float*)d_out;

  hipLaunchKernelGGL(k_all, dim3(512), dim3(256), 0, stream,
                     ctx_ids, tgt_ids, ctx_len, tgt_len, toff, emb,
                     Wl, bl, wat, bat, bo, Wo, Mt, Mc, Q, outp);
}

// Round 4
// 486.304 us; speedup vs baseline: 1.5776x; 1.5776x over previous
//
#include <hip/hip_runtime.h>
#include <cstdint>

// MemNet, fully fused, minimal producer->consumer sync, fence-free:
// Q[b,l,j] = v_loc[b,l] * (mem[b,l] . M_j),  25+3 projection columns:
//   col 0        : w0 = w_attn[0:D]
//   col 1+k      : U_k = W_lin^k u, k=0..5   (u = w_attn[D:2D])
//   col 7+6c+k   : Y_{k,c} = W_lin^k W_out[:,c], k=0..5
//   col 25+c     : Y_{6,c}  (hop phase only)
// All shared Mt/Mc/Q locations are WRITE-ONCE and written via agent-scope
// relaxed atomic stores (sc1: write-through to Infinity Cache, no L2 dirty
// copies). No location is read before its write within the dispatch (the
// ws poison fill's L2 lines are invalidated at the kernel boundary), so no
// consumer acquire/invalidate fences are needed -- consumers' first touch
// misses L2 and reads fresh from IC. Sync: release fetch_add + relaxed spin.
// Phases: chain (64 blocks, ticket mini-barriers) || emb prefetch (others)
//   -> wait chain step5 -> gemm (tile=bid) -> per-batch release
//   -> hop blocks (448..511) wait 8 producers + step6 -> hop recursion.
// Deadlock-free WITHOUT co-residency: producers have lower blockIdx than
// their consumers, blocks dispatch in order, and bid<448 blocks exit after
// gemm freeing slots; spins are also guard-bounded (fail loud, never hang).
// Epoch per launch: g_ep ticket / 512 (launches stream-serialized).

#define DD 1024
#define LL 512
#define MTS 32
#define NCHAIN 64u

__device__ unsigned g_ep;       // +512 per launch
__device__ unsigned g_c[8];     // chain step arrivals: +64 per launch each
__device__ unsigned g_q[64];    // per-batch Q-ready: +8 per launch each

__device__ __forceinline__ void waitge(unsigned* p, unsigned tgt)
{
  int guard = 0;
  while (__hip_atomic_load(p, __ATOMIC_RELAXED, __HIP_MEMORY_SCOPE_AGENT) < tgt) {
    __builtin_amdgcn_s_sleep(8);
    if (++guard > (1 << 17)) break;   // fail loud, never hang
  }
}

// write-through (agent scope) store: lands at the coherent point (IC)
__device__ __forceinline__ void stg(float* p, float v) {
  __hip_atomic_store(p, v, __ATOMIC_RELAXED, __HIP_MEMORY_SCOPE_AGENT);
}

__device__ __forceinline__ void chain_bar(int k)
{
  __syncthreads();   // drains vmcnt: all sc1 stores at IC before arrival
  if (threadIdx.x == 0) {
    unsigned t = __hip_atomic_fetch_add(&g_c[k], 1u, __ATOMIC_RELEASE,
                                        __HIP_MEMORY_SCOPE_AGENT);
    waitge(&g_c[k], (t / NCHAIN + 1u) * NCHAIN);
  }
  __syncthreads();
}

union SMem {
  struct { float stag[4][64 * 33]; float qp[4][64][25]; } g;        // 59392 B
  struct { float Qs[25 * LL]; float va[DD]; float red[36 * 4]; } h; // 55872 B
};

__device__ __forceinline__ void keep4(float4 v) {
  asm volatile("" :: "v"(v.x), "v"(v.y), "v"(v.z), "v"(v.w));
}

// warm one 64-row tile (256 KB) of gathered embeddings into L2/IC
__device__ __forceinline__ void prefetch_tile(const int* __restrict__ ctx_ids,
                                              const float* __restrict__ emb,
                                              int tile, int tid)
{
  int rowbase = tile * 64;
#pragma unroll 4
  for (int r = 0; r < 64; ++r) {
    int rid = ctx_ids[rowbase + r];
    float4 v = ((const float4*)(emb + (size_t)rid * DD))[tid];
    keep4(v);
  }
}

template <bool ISMAX>
__device__ __forceinline__ void breduce(float* v, int n, float* lds, int tid)
{
  int wv = __builtin_amdgcn_readfirstlane(tid >> 6);
  int ln = tid & 63;
  for (int q = 0; q < n; ++q) {
    float x = v[q];
#pragma unroll
    for (int m = 1; m < 64; m <<= 1) {
      float o = __shfl_xor(x, m, 64);
      x = ISMAX ? fmaxf(x, o) : x + o;
    }
    if (ln == 0) lds[q * 4 + wv] = x;
  }
  __syncthreads();
  for (int q = 0; q < n; ++q) {
    float a = lds[q * 4 + 0], b = lds[q * 4 + 1];
    float c = lds[q * 4 + 2], d = lds[q * 4 + 3];
    v[q] = ISMAX ? fmaxf(fmaxf(a, b), fmaxf(c, d)) : ((a + b) + (c + d));
  }
  __syncthreads();
}

__global__ __launch_bounds__(256, 2) void k_all(
    const int* __restrict__ ctx_ids, const int* __restrict__ tgt_ids,
    const int* __restrict__ ctx_len, const int* __restrict__ tgt_len,
    const int* __restrict__ toff,    const float* __restrict__ emb,
    const float* __restrict__ Wl,    const float* __restrict__ bl,
    const float* __restrict__ wat,   const float* __restrict__ bat,
    const float* __restrict__ bo,    const float* __restrict__ Wo,
    float* __restrict__ Mt, float* __restrict__ Mc,
    float* __restrict__ Q,  float* __restrict__ out)
{
  __shared__ SMem sm;
  const int tid = threadIdx.x;
  const int bid = blockIdx.x;
  const int wv  = __builtin_amdgcn_readfirstlane(tid >> 6);
  const int ln  = tid & 63;
  const int rowbase = bid * 64;

  unsigned E = 0;
  if (tid == 0)
    E = __hip_atomic_fetch_add(&g_ep, 1u, __ATOMIC_RELAXED,
                               __HIP_MEMORY_SCOPE_AGENT) / 512u;

  if (bid < (int)NCHAIN) {
    // ---------- chain: init base columns, then 6 matvec steps -----------
    if (tid < 16) {
      int d = bid * 16 + tid;
      float w0 = wat[d], u0 = wat[DD + d];
      stg(&Mt[d * MTS + 0], w0); stg(&Mc[0 * DD + d], w0);
      stg(&Mt[d * MTS + 1], u0); stg(&Mc[1 * DD + d], u0);
#pragma unroll
      for (int c = 0; c < 3; ++c) {
        float y = Wo[d * 3 + c];
        int col = 7 + 6 * c;
        stg(&Mt[d * MTS + col], y); stg(&Mc[col * DD + d], y);
      }
    }
    chain_bar(0);
    int g    = bid * 256 + tid;     // [0, 16384)
    int q    = g & 3;               // column group: 0=U, 1..3=Y_{c=q-1}
    int part = (g >> 2) & 3;        // j-slice [part*256, part*256+256)
    int row  = g >> 4;              // [0, 1024)
    const float* wr0 = Wl + (size_t)row * DD + part * 256;
    for (int s = 1; s <= 6; ++s) {
      int cin = (q == 0) ? s : q * 6 + s;
      const float* mc = Mc + (size_t)cin * DD + part * 256;
      float4 a4 = {0.f, 0.f, 0.f, 0.f};
#pragma unroll 8
      for (int j = 0; j < 256; j += 4) {
        float4 w = *(const float4*)(wr0 + j);
        float4 m = *(const float4*)(mc + j);
        a4.x += w.x * m.x; a4.y += w.y * m.y;
        a4.z += w.z * m.z; a4.w += w.w * m.w;
      }
      float sdot = (a4.x + a4.y) + (a4.z + a4.w);
      sdot += __shfl_xor(sdot, 4, 64);   // reduce the 4 j-slices
      sdot += __shfl_xor(sdot, 8, 64);
      if (part == 0) {
        if (s <= 5) {
          int co = 1 + q * 6 + s;
          stg(&Mt[row * MTS + co], sdot); stg(&Mc[co * DD + row], sdot);
        } else if (q > 0) {
          stg(&Mc[(24 + q) * DD + row], sdot);   // cols 25..27, hop-only
        }
      }
      chain_bar(s);
    }
  } else {
    // ---------- everyone else: warm the embedding gather into L2/IC ----
    prefetch_tile(ctx_ids, emb, bid, tid);
    if (bid < 2 * (int)NCHAIN)
      prefetch_tile(ctx_ids, emb, bid - (int)NCHAIN, tid);  // chain's tiles
  }

  // ---------- gemm: tile = bid (64 ctx rows, wave = k-quarter) ---------
  {
    float* sw = sm.g.stag[wv];
    int myid = ctx_ids[rowbase + ln];
    const float* base[8];
#pragma unroll
    for (int ii = 0; ii < 8; ++ii) {
      int rid = __shfl(myid, ii * 8 + (ln >> 3), 64);
      base[ii] = emb + (size_t)rid * DD;
    }
    int p4 = (ln & 7) * 4;
    int k0 = wv * 256;
    float acc[25];
#pragma unroll
    for (int j = 0; j < 25; ++j) acc[j] = 0.f;

    // issue first-chunk loads BEFORE the chain wait (hide latency in spin)
    float4 buf[8];
#pragma unroll
    for (int ii = 0; ii < 8; ++ii)
      buf[ii] = *(const float4*)(base[ii] + k0 + p4);

    if (tid == 0) waitge(&g_c[5], NCHAIN * (E + 1u));  // cols 0..24 ready
    __syncthreads();

    for (int ch = 0; ch < 8; ++ch) {
#pragma unroll
      for (int ii = 0; ii < 8; ++ii) {
        int r = ii * 8 + (ln >> 3);
        int a = r * 33 + p4;
        sw[a + 0] = buf[ii].x; sw[a + 1] = buf[ii].y;
        sw[a + 2] = buf[ii].z; sw[a + 3] = buf[ii].w;
      }
      if (ch < 7) {
        int kb = k0 + (ch + 1) * 32;
#pragma unroll
        for (int ii = 0; ii < 8; ++ii)
          buf[ii] = *(const float4*)(base[ii] + kb + p4);
      }
      __builtin_amdgcn_s_waitcnt(0xc07f);  // lgkmcnt(0): same-wave LDS visibility
      const float* mrow = Mt + (size_t)(k0 + ch * 32) * MTS;  // wave-uniform
#pragma unroll 4
      for (int kk = 0; kk < 32; ++kk) {
        float mv = sw[ln * 33 + kk];
#pragma unroll
        for (int j = 0; j < 25; ++j) acc[j] += mv * mrow[kk * MTS + j];
      }
    }
#pragma unroll
    for (int j = 0; j < 25; ++j) sm.g.qp[wv][ln][j] = acc[j];
    __syncthreads();

    int b = rowbase >> 9;
    int l0 = rowbase & 511;
    int clen = ctx_len[b];
    int off = toff[b];
    float fclen = (float)clen;
    for (int i = tid; i < 1600; i += 256) {
      int j = i >> 6, r = i & 63;
      float s = sm.g.qp[0][r][j] + sm.g.qp[1][r][j] +
                sm.g.qp[2][r][j] + sm.g.qp[3][r][j];
      int l = l0 + r;
      float vl = (l < clen) ? (1.f - fabsf((float)(l - off)) / fclen) : 0.f;
      stg(&Q[((size_t)b * 25 + j) * LL + l], s * vl);
    }
  }
  __syncthreads();   // drains vmcnt: Q stores at IC before release
  if (tid == 0)
    __hip_atomic_fetch_add(&g_q[bid >> 3], 1u, __ATOMIC_RELEASE,
                           __HIP_MEMORY_SCOPE_AGENT);

  // ---------- hop recursion: blocks 448..511 handle batch bid-448 ------
  if (bid < 448) return;
  {
    int b = bid - 448;
    if (tid == 0) {
      waitge(&g_q[b], 8u * (E + 1u));          // 8 Q producers of batch b
      waitge(&g_c[6], NCHAIN * (E + 1u));      // cols 25..27 (step 6)
    }
    __syncthreads();

    float* Qs = sm.h.Qs;
    float* va = sm.h.va;
    float* red = sm.h.red;

    for (int i = tid; i < 25 * LL; i += 256)
      Qs[i] = Q[(size_t)b * (25 * LL) + i];

    int tl = tgt_len[b];
    float inv_tl = 1.f / (float)tl;
    for (int d = tid; d < DD; d += 256) {
      float s = 0.f;
#pragma unroll
      for (int t = 0; t < 8; ++t)
        if (t < tl) s += emb[(size_t)tgt_ids[b * 8 + t] * DD + d];
      va[d] = s * inv_tl;
    }
    __syncthreads();

    // 32 dots: p[0..5]=va.U_k, p[6..8]=va.Y6c, p[9..13]=b.U_k(k<5), p[14+6c+k]=b.Y_{k,c}
    float p[32];
#pragma unroll
    for (int q = 0; q < 32; ++q) p[q] = 0.f;
    for (int d = tid; d < DD; d += 256) {
      float vad = va[d], bd = bl[d];
#pragma unroll
      for (int k = 0; k < 6; ++k) {
        float u = Mc[(1 + k) * DD + d];
        p[k] += vad * u;
        if (k < 5) p[9 + k] += bd * u;
      }
#pragma unroll
      for (int c = 0; c < 3; ++c) {
        p[6 + c] += vad * Mc[(25 + c) * DD + d];
#pragma unroll
        for (int k = 0; k < 6; ++k)
          p[14 + c * 6 + k] += bd * Mc[(7 + 6 * c + k) * DD + d];
      }
    }
    breduce<false>(p, 32, red, tid);

    float tcur[6], rc[3], beta[5], gam[18];
#pragma unroll
    for (int k = 0; k < 6; ++k) tcur[k] = p[k];
#pragma unroll
    for (int c = 0; c < 3; ++c) rc[c] = p[6 + c];
#pragma unroll
    for (int k = 0; k < 5; ++k) beta[k] = p[9 + k];
#pragma unroll
    for (int q = 0; q < 18; ++q) gam[q] = p[14 + q];

    int clen = ctx_len[b];
    float batt = bat[0];
    int l1 = tid, l2 = tid + 256;

    for (int h = 0; h < 6; ++h) {
      float s_h = tcur[0];
      float sc1 = -1e30f, sc2 = -1e30f;
      if (l1 < clen) sc1 = tanhf(Qs[l1] + s_h + batt);
      if (l2 < clen) sc2 = tanhf(Qs[l2] + s_h + batt);
      float mx = fmaxf(sc1, sc2);
      breduce<true>(&mx, 1, red, tid);

      float pe[9];
#pragma unroll
      for (int q = 0; q < 9; ++q) pe[q] = 0.f;
      int kd = 5 - h;
      if (l1 < clen) {
        float e = expf(sc1 - mx);
        pe[0] += e;
        for (int k = 0; k <= 4 - h; ++k) pe[1 + k] += e * Qs[(1 + k) * LL + l1];
#pragma unroll
        for (int c = 0; c < 3; ++c) pe[6 + c] += e * Qs[(7 + 6 * c + kd) * LL + l1];
      }
      if (l2 < clen) {
        float e = expf(sc2 - mx);
        pe[0] += e;
        for (int k = 0; k <= 4 - h; ++k) pe[1 + k] += e * Qs[(1 + k) * LL + l2];
#pragma unroll
        for (int c = 0; c < 3; ++c) pe[6 + c] += e * Qs[(7 + 6 * c + kd) * LL + l2];
      }
      breduce<false>(pe, 9, red, tid);

      float invS = 1.f / pe[0];
      for (int k = 0; k <= 4 - h; ++k)
        tcur[k] = pe[1 + k] * invS + tcur[k + 1] + beta[k];
#pragma unroll
      for (int c = 0; c < 3; ++c)
        rc[c] = pe[6 + c] * invS + rc[c] + gam[c * 6 + kd];
    }
    if (tid < 3) out[b * 3 + tid] = rc[tid] + bo[tid];
  }
}

extern "C" void kernel_launch(void* const* d_in, const int* in_sizes, int n_in,
                              void* d_out, int out_size, void* d_ws, size_t ws_size,
                              hipStream_t stream)
{
  const int*   ctx_ids = (const int*)d_in[0];
  const int*   tgt_ids = (const int*)d_in[1];
  const int*   ctx_len = (const int*)d_in[2];
  const int*   tgt_len = (const int*)d_in[3];
  const int*   toff    = (const int*)d_in[4];
  const float* emb     = (const float*)d_in[5];
  const float* Wl      = (const float*)d_in[6];
  const float* bl      = (const float*)d_in[7];
  const float* wat     = (const float*)d_in[8];
  const float* bat     = (const float*)d_in[9];
  const float* Wo      = (const float*)d_in[10];
  const float* bo      = (const float*)d_in[11];
  float* ws = (float*)d_ws;
  float* Mt = ws;                 // 1024*32
  float* Mc = ws + 32768;         // 32*1024
  float* Q  = ws + 65536;         // 64*25*512
  float* outp = (float*)d_out;

  hipLaunchKernelGGL(k_all, dim3(512), dim3(256), 0, stream,
                     ctx_ids, tgt_ids, ctx_len, tgt_len, toff, emb,
                     Wl, bl, wat, bat, bo, Wo, Mt, Mc, Q, outp);
}